// Round 17
// baseline (256.566 us; speedup 1.0000x reference)
//
#include <hip/hip_runtime.h>
#include <hip/hip_fp16.h>
#include <math.h>

#define Hh 96
#define Ww 96
#define NPIX 9216
#define RAD 15
#define TAPS 31
#define NCH 144            // chunks of 64 sorted pixels
#define NBIN 4096
#define GRIDK 512          // buildK blocks (2048 waves, grid-stride over tasks)
#define GRIDM 512          // matvec blocks
#define EPSV 1e-20f
#define LOG2E 1.4426950408889634f
#define CUT2 42.0f         // box-box prune: k < 2^-30 beyond => safe (err ~1e-5)

// ---- ws layout (4-byte units) ----
#define OFF_F    0                 // 8*NPIX feat_sorted: h0..h4, a, q, pad
#define OFF_Q0   73728             // NPIX  q ping (original order, combine halo)
#define OFF_Q1   82944             // NPIX  q pong
#define OFF_QS   92160             // NPIX  q SORTED order (matvec input)
#define OFF_CBI  101376            // NPIX  bilateral colsum, SORTED order
#define OFF_BV   110592            // NPIX  bilateral q-filter, SORTED order
#define OFF_ROWW 119808            // 96
#define OFF_WTAB 119904            // 32
#define OFF_BBOX 119936            // NCH*12
// int regions
#define OFF_HIST 121664            // 4096
#define OFF_BASE 125760            // 4096
#define OFF_INV  129856            // NPIX  orig n -> sorted pos
#define OFF_OFS  139072            // NCH+1
#define OFF_WORK 139217            // NCH*NCH flat worklist (chunk ids, grouped by jg)
#define OFF_NTASK 159953           // 1
#define OFF_TASK 159954            // <=NCH*36 tasks: (len<<28)|(jg<<20)|start
#define OFF_K    165888            // item stride 2048 u32: fp16 K [item][ipair][j]

__device__ __forceinline__ int color_key(float r, float g, float b){
  int rq = min(15, (int)r >> 4);
  int gq = min(15, (int)g >> 4);
  int bq = min(15, (int)b >> 4);
  int key = 0;
  #pragma unroll
  for (int k=0;k<4;k++){
    key |= ((rq>>k)&1) << (3*k+2);
    key |= ((gq>>k)&1) << (3*k+1);
    key |= ((bq>>k)&1) << (3*k);
  }
  return key;
}

// A: zero BV/CBI/hist + spatial tables
__global__ __launch_bounds__(256) void prepA_kernel(float* __restrict__ ws){
  int idx = blockIdx.x*256 + threadIdx.x;
  int* W = (int*)ws;
  if (idx < NPIX){ ws[OFF_BV+idx]=0.f; ws[OFF_CBI+idx]=0.f; }
  if (idx < NBIN) W[OFF_HIST+idx] = 0;
  if (blockIdx.x == 94 && threadIdx.x < Hh){
    int t = threadIdx.x;
    float s = 0.f;
    for (int yy=0; yy<Hh; ++yy){ float d=(float)(yy-t); s += expf(-d*d*(1.0f/18.0f)); }
    ws[OFF_ROWW + t] = s;                 // full 1-D colsum (spatial norm)
  }
  if (blockIdx.x == 95 && threadIdx.x < TAPS){
    int d = threadIdx.x - RAD;
    ws[OFF_WTAB + threadIdx.x] = expf(-(float)(d*d)*(1.0f/18.0f));
  }
}

// B: color histogram
__global__ __launch_bounds__(256) void prepB_kernel(const float* __restrict__ image,
                                                    float* __restrict__ ws){
  int n = blockIdx.x*256 + threadIdx.x;
  int key = color_key(image[n], image[NPIX+n], image[2*NPIX+n]);
  atomicAdd((int*)ws + OFF_HIST + key, 1);
}

// C: exclusive scan of 4096 bins (1 block)
__global__ __launch_bounds__(256) void prepC_kernel(float* __restrict__ ws){
  __shared__ int part[256];
  const int* hist = (const int*)ws + OFF_HIST;
  int* base = (int*)ws + OFF_BASE;
  int t = threadIdx.x;
  int loc[16]; int s = 0;
  #pragma unroll
  for (int i=0;i<16;i++){ loc[i]=s; s += hist[t*16+i]; }
  part[t] = s; __syncthreads();
  for (int off=1; off<256; off<<=1){
    int v = (t>=off) ? part[t-off] : 0;
    __syncthreads(); part[t] += v; __syncthreads();
  }
  int b = (t==0)?0:part[t-1];
  #pragma unroll
  for (int i=0;i<16;i++) base[t*16+i] = b + loc[i];
}

// D: scatter + sorted feature build (q in F slot 6) + initial q (orig + sorted)
__global__ __launch_bounds__(256) void prepD_kernel(const float* __restrict__ image,
                                                    const float* __restrict__ logits,
                                                    float* __restrict__ ws){
  int n = blockIdx.x*256 + threadIdx.x;
  int* W = (int*)ws;
  float r=image[n], g=image[NPIX+n], bl=image[2*NPIX+n];
  int key = color_key(r,g,bl);
  int pos = atomicAdd(W + OFF_BASE + key, 1);
  W[OFF_INV + n] = pos;
  int y=n/Ww, x=n%Ww;
  const float c=0.7213475205f;    // 0.5/ln2
  const float sc=1.2011224088f;   // sqrt(2c)
  float f0=(float)y*(1.f/160.f), f1=(float)x*(1.f/160.f);
  float f2=r*(1.f/3.f), f3=g*(1.f/3.f), f4=bl*(1.f/3.f);
  float a=c*(f0*f0+f1*f1+f2*f2+f3*f3+f4*f4);
  float q = 1.f/(1.f + __builtin_amdgcn_exp2f((logits[NPIX+n]-logits[n])*LOG2E));
  float* F = ws + OFF_F + (size_t)pos*8;
  F[0]=sc*f0; F[1]=sc*f1; F[2]=sc*f2; F[3]=sc*f3; F[4]=sc*f4;
  F[5]=a; F[6]=q; F[7]=0.f;
  ws[OFF_Q0 + n] = q;
  ws[OFF_QS + pos] = q;
}

// E1: per-chunk 5-D bbox, one wave per chunk
__global__ __launch_bounds__(256) void prepE1_kernel(float* __restrict__ ws){
  const int lane = threadIdx.x & 63, wid = threadIdx.x >> 6;
  int ch = blockIdx.x*4 + wid;
  if (ch >= NCH) return;
  const float* Fp = ws + OFF_F + ((size_t)ch*64 + lane)*8;
  float4 A = *(const float4*)Fp;
  float4 B4 = *(const float4*)(Fp+4);
  float mn[5]={A.x,A.y,A.z,A.w,B4.x}, mx[5]={A.x,A.y,A.z,A.w,B4.x};
  #pragma unroll
  for (int m=32; m; m>>=1){
    #pragma unroll
    for (int d=0;d<5;d++){
      mn[d]=fminf(mn[d], __shfl_xor(mn[d], m));
      mx[d]=fmaxf(mx[d], __shfl_xor(mx[d], m));
    }
  }
  if (lane == 0){
    float* bb = ws + OFF_BBOX + ch*12;
    #pragma unroll
    for (int d=0;d<5;d++){ bb[d]=mn[d]; bb[5+d]=mx[d]; }
  }
}

// E2: cull (box-box) + scan + pack flat worklist + pack 4-chunk TASK list
__global__ __launch_bounds__(256) void prepE2_kernel(float* __restrict__ ws){
  __shared__ float bbl[NCH*12];
  __shared__ int part[256];
  __shared__ int cnt[NCH];
  const int t = threadIdx.x, lane = t & 63, wid = t >> 6;
  int* W = (int*)ws;

  for (int i=t; i<NCH*12; i+=256) bbl[i] = ws[OFF_BBOX + i];
  __syncthreads();

  // pass 1: survivor counts
  for (int jg = wid; jg < NCH; jg += 4){
    const float* jb = &bbl[jg*12];
    int base = 0;
    #pragma unroll
    for (int r2=0;r2<3;r2++){
      int c2 = lane + 64*r2;
      bool sv = false;
      if (c2 < NCH){
        const float* cb = &bbl[c2*12];
        float s2 = 0.f;
        #pragma unroll
        for (int d=0;d<5;d++){
          float gap = fmaxf(0.f, fmaxf(cb[d]-jb[5+d], jb[d]-cb[5+d]));
          s2 = fmaf(gap, gap, s2);
        }
        sv = (s2 <= CUT2);
      }
      base += __popcll(__ballot(sv));
    }
    if (lane == 0) cnt[jg] = base;
  }
  __syncthreads();

  // scan 1: worklist offsets
  int v = (t < NCH) ? cnt[t] : 0;
  part[t] = v; __syncthreads();
  for (int off=1; off<256; off<<=1){
    int u = (t>=off) ? part[t-off] : 0;
    __syncthreads(); part[t] += u; __syncthreads();
  }
  if (t == 0) W[OFF_OFS] = 0;
  if (t < NCH) W[OFF_OFS + t + 1] = part[t];
  __syncthreads();

  // pass 2: pack worklist (chunk ids, grouped by jg)
  for (int jg = wid; jg < NCH; jg += 4){
    const float* jb = &bbl[jg*12];
    int base = (jg == 0) ? 0 : part[jg-1];
    #pragma unroll
    for (int r2=0;r2<3;r2++){
      int c2 = lane + 64*r2;
      bool sv = false;
      if (c2 < NCH){
        const float* cb = &bbl[c2*12];
        float s2 = 0.f;
        #pragma unroll
        for (int d=0;d<5;d++){
          float gap = fmaxf(0.f, fmaxf(cb[d]-jb[5+d], jb[d]-cb[5+d]));
          s2 = fmaf(gap, gap, s2);
        }
        sv = (s2 <= CUT2);
      }
      unsigned long long m = __ballot(sv);
      if (sv){
        int pos = __popcll(m & ((1ull<<lane)-1ull));
        W[OFF_WORK + base + pos] = c2;
      }
      base += __popcll(m);
    }
  }
  __syncthreads();

  // scan 2: task offsets (ceil(cnt/4) tasks per jg), then emit tasks
  int v2 = (t < NCH) ? ((cnt[t]+3)>>2) : 0;
  part[t] = v2; __syncthreads();
  for (int off=1; off<256; off<<=1){
    int u = (t>=off) ? part[t-off] : 0;
    __syncthreads(); part[t] += u; __syncthreads();
  }
  if (t < NCH){
    int tb = (t==0) ? 0 : part[t-1];
    int sg = W[OFF_OFS + t];
    int cn = cnt[t];
    for (int k=0, ti=0; k<cn; k+=4, ++ti){
      unsigned int len = (unsigned int)min(4, cn-k);
      // (len<<28)|(jg<<20)|start — jg<=143 in 8 bits, start<=20736 in 20 bits
      ((unsigned int*)W)[OFF_TASK + tb + ti] =
          (len<<28) | ((unsigned int)t<<20) | (unsigned int)(sg+k);
    }
  }
  if (t == NCH-1) W[OFF_NTASK] = part[NCH-1];
}

// buildK: one wave per task (jg, <=4 chunks). 4 interleaved chunks => 4
// independent exp/acc chains per lane. K stored [item][ipair][j] fp16
// (coalesced 256B stores). One atomic pair per task (sorted order).
__global__ __launch_bounds__(256) void buildK_kernel(float* __restrict__ ws){
  __shared__ float chunk[4][4*512];
  const int lane = threadIdx.x & 63, wid = threadIdx.x >> 6;
  int* W = (int*)ws;
  const int ntask = W[OFF_NTASK];
  const int* work = W + OFF_WORK;
  const unsigned int* tasks = (const unsigned int*)W + OFF_TASK;
  const float* F  = ws + OFF_F;
  unsigned int* Kb = (unsigned int*)ws + OFF_K;
  float* s = &chunk[wid][0];
  const int NW = GRIDK*4;

  for (int task = blockIdx.x*4 + wid; task < ntask; task += NW){
    unsigned int tk = tasks[task];
    int len = (int)(tk >> 28);
    int jg  = (int)((tk >> 20) & 0xFFu);
    int start = (int)(tk & 0xFFFFFu);
    int js = jg*64 + lane;
    float4 jA = *(const float4*)(F + (size_t)js*8);
    float4 jB = *(const float4*)(F + (size_t)js*8 + 4);
    const float h0=jA.x,h1=jA.y,h2=jA.z,h3=jA.w,h4=jB.x,na=-jB.y;

    #define BK_STAGE(k)                                                        \
    if (k < len){                                                              \
      int cc = work[start+k];                                                  \
      const float* src = F + (size_t)cc*512;                                   \
      *(float4*)(s + k*512 + lane*8)     = *(const float4*)(src + lane*8);     \
      *(float4*)(s + k*512 + lane*8 + 4) = *(const float4*)(src + lane*8 + 4); \
    }
    BK_STAGE(0) BK_STAGE(1) BK_STAGE(2) BK_STAGE(3)
    #undef BK_STAGE

    float aB0=0.f,aB1=0.f,aB2=0.f,aB3=0.f;
    float aC0=0.f,aC1=0.f,aC2=0.f,aC3=0.f;

    #pragma unroll 4
    for (int ii2=0; ii2<32; ii2++){
      #define BK_BODY(k, AB, AC)                                               \
      if (k < len){                                                            \
        const float* p = s + k*512 + ii2*16;                                   \
        float4 w0 = *(const float4*)(p);    float4 w1 = *(const float4*)(p+4); \
        float4 u0 = *(const float4*)(p+8);  float4 u1 = *(const float4*)(p+12);\
        float e0 = na - w1.y;                                                  \
        e0=fmaf(h0,w0.x,e0); e0=fmaf(h1,w0.y,e0); e0=fmaf(h2,w0.z,e0);         \
        e0=fmaf(h3,w0.w,e0); e0=fmaf(h4,w1.x,e0);                              \
        float k0 = __builtin_amdgcn_exp2f(e0);                                 \
        float e1 = na - u1.y;                                                  \
        e1=fmaf(h0,u0.x,e1); e1=fmaf(h1,u0.y,e1); e1=fmaf(h2,u0.z,e1);         \
        e1=fmaf(h3,u0.w,e1); e1=fmaf(h4,u1.x,e1);                              \
        float k1 = __builtin_amdgcn_exp2f(e1);                                 \
        AC += k0 + k1;                                                         \
        AB = fmaf(k0, w1.z, AB); AB = fmaf(k1, u1.z, AB);                      \
        __half2 hv = __floats2half2_rn(k0, k1);                                \
        Kb[(size_t)(start+k)*2048 + ii2*64 + lane] =                           \
            *reinterpret_cast<unsigned int*>(&hv);                             \
      }
      BK_BODY(0, aB0, aC0) BK_BODY(1, aB1, aC1)
      BK_BODY(2, aB2, aC2) BK_BODY(3, aB3, aC3)
      #undef BK_BODY
    }
    atomicAdd(ws + OFF_BV  + js, (aB0+aB1)+(aB2+aB3));
    atomicAdd(ws + OFF_CBI + js, (aC0+aC1)+(aC2+aC3));
  }
}

// matvec: one wave per task; 4 interleaved items (independent acc chains);
// coalesced 256B K loads; q broadcast from LDS; one atomic per task.
__global__ __launch_bounds__(256) void matvec_kernel(float* __restrict__ ws){
  __shared__ float qsh[4][4*64];
  const int lane = threadIdx.x & 63, wid = threadIdx.x >> 6;
  const int* W = (const int*)ws;
  const int ntask = W[OFF_NTASK];
  const int* work = W + OFF_WORK;
  const unsigned int* tasks = (const unsigned int*)W + OFF_TASK;
  const unsigned int* Kb = (const unsigned int*)ws + OFF_K;
  float* ql = &qsh[wid][0];
  const int NW = GRIDM*4;

  for (int task = blockIdx.x*4 + wid; task < ntask; task += NW){
    unsigned int tk = tasks[task];
    int len = (int)(tk >> 28);
    int jg  = (int)((tk >> 20) & 0xFFu);
    int start = (int)(tk & 0xFFFFFu);
    int js = jg*64 + lane;

    #define MV_STAGE(k)                                                        \
    if (k < len){ int cc = work[start+k]; ql[k*64 + lane] = ws[OFF_QS + cc*64 + lane]; }
    MV_STAGE(0) MV_STAGE(1) MV_STAGE(2) MV_STAGE(3)
    #undef MV_STAGE

    float a0=0.f,a1=0.f,a2=0.f,a3=0.f;
    #pragma unroll 4
    for (int ii2=0; ii2<32; ii2++){
      #define MV_BODY(k, ACC)                                                  \
      if (k < len){                                                            \
        unsigned int kk = Kb[(size_t)(start+k)*2048 + ii2*64 + lane];          \
        __half2 hv = *reinterpret_cast<__half2*>(&kk);                         \
        float q0 = ql[k*64 + 2*ii2], q1 = ql[k*64 + 2*ii2 + 1];                \
        ACC = fmaf(__low2float(hv), q0, ACC);                                  \
        ACC = fmaf(__high2float(hv), q1, ACC);                                 \
      }
      MV_BODY(0, a0) MV_BODY(1, a1) MV_BODY(2, a2) MV_BODY(3, a3)
      #undef MV_BODY
    }
    atomicAdd(ws + OFF_BV + js, (a0+a1)+(a2+a3));
  }
}

// combine: separable spatial conv + message/compat/update + next-iter q.
__global__ __launch_bounds__(256) void combine_kernel(const float* __restrict__ logits,
                                                      const float* __restrict__ Wsp,
                                                      const float* __restrict__ Wbi,
                                                      const float* __restrict__ Cm,
                                                      float* __restrict__ ws,
                                                      float* __restrict__ out,
                                                      const float* __restrict__ qsrc,
                                                      float* __restrict__ qdst){
  __shared__ float tq[46][48];
  __shared__ float tr[46][17];
  __shared__ float wt[TAPS];
  int tx = threadIdx.x & 15, ty = threadIdx.x >> 4;
  int bx = blockIdx.x % 6, by = blockIdx.x / 6;
  int x0 = bx*16, y0 = by*16;

  for (int idx = threadIdx.x; idx < 46*46; idx += 256){
    int ly = idx / 46, lx = idx % 46;
    int gy = y0 - RAD + ly, gx = x0 - RAD + lx;
    float v = 0.f;
    if (gy >= 0 && gy < Hh && gx >= 0 && gx < Ww) v = qsrc[gy*Ww + gx];
    tq[ly][lx] = v;
  }
  if (threadIdx.x < TAPS) wt[threadIdx.x] = ws[OFF_WTAB + threadIdx.x];
  __syncthreads();

  for (int idx = threadIdx.x; idx < 46*16; idx += 256){
    int ly = idx >> 4, lx = idx & 15;
    float in = 0.f;
    #pragma unroll
    for (int dx=0; dx<TAPS; dx++) in = fmaf(wt[dx], tq[ly][lx+dx], in);
    tr[ly][lx] = in;
  }
  __syncthreads();

  int y = y0 + ty, x = x0 + tx, j = y*Ww + x;
  float S = 0.f;
  #pragma unroll
  for (int dy=0; dy<TAPS; dy++) S = fmaf(wt[dy], tr[ty+dy][tx], S);

  int js = ((const int*)ws)[OFF_INV + j];
  float Bv = ws[OFF_BV + js];
  ws[OFF_BV + js] = 0.f;                      // reset for next iteration's atomics
  float Cb = ws[OFF_CBI + js];
  float nb  = 1.0f/(Cb + EPSV);
  float Csp = ws[OFF_ROWW + y] * ws[OFF_ROWW + x];
  float nsp = 1.0f/(Csp + EPSV);

  float sp0 = S*nsp,  sp1 = (Csp - S)*nsp;    // q1 = 1 - q0 identity
  float bi0 = Bv*nb,  bi1 = (Cb - Bv)*nb;

  float m0 = Wsp[0]*sp0 + Wsp[1]*sp1 + Wbi[0]*bi0 + Wbi[1]*bi1;
  float m1 = Wsp[2]*sp0 + Wsp[3]*sp1 + Wbi[2]*bi0 + Wbi[3]*bi1;
  float cm0 = Cm[0]*m0 + Cm[1]*m1;
  float cm1 = Cm[2]*m0 + Cm[3]*m1;

  float o0 = logits[j]        - cm0;
  float o1 = logits[NPIX + j] - cm1;
  out[j]        = o0;
  out[NPIX + j] = o1;

  float qn = 1.0f / (1.0f + __builtin_amdgcn_exp2f((o1-o0)*LOG2E));
  qdst[j] = qn;
  ws[OFF_QS + js] = qn;
}

extern "C" void kernel_launch(void* const* d_in, const int* in_sizes, int n_in,
                              void* d_out, int out_size, void* d_ws, size_t ws_size,
                              hipStream_t stream){
  const float* image  = (const float*)d_in[0];
  const float* logits = (const float*)d_in[1];
  const float* Wsp    = (const float*)d_in[2];
  const float* Wbi    = (const float*)d_in[3];
  const float* Cm     = (const float*)d_in[4];
  float* out = (float*)d_out;
  float* ws  = (float*)d_ws;

  float* qbuf[2] = { ws + OFF_Q0, ws + OFF_Q1 };

  prepA_kernel <<<96, 256, 0, stream>>>(ws);
  prepB_kernel <<<36, 256, 0, stream>>>(image, ws);
  prepC_kernel <<<1, 256, 0, stream>>>(ws);
  prepD_kernel <<<36, 256, 0, stream>>>(image, logits, ws);
  prepE1_kernel<<<36, 256, 0, stream>>>(ws);
  prepE2_kernel<<<1, 256, 0, stream>>>(ws);

  // iteration 0: build fp16 K + colsum + q-filter in one pass
  buildK_kernel<<<GRIDK, 256, 0, stream>>>(ws);
  combine_kernel<<<36, 256, 0, stream>>>(logits, Wsp, Wbi, Cm, ws, out,
                                         qbuf[0], qbuf[1]);
  // iterations 1..4: stream K
  for (int t=1; t<5; ++t){
    matvec_kernel<<<GRIDM, 256, 0, stream>>>(ws);
    combine_kernel<<<36, 256, 0, stream>>>(logits, Wsp, Wbi, Cm, ws, out,
                                           qbuf[t&1], qbuf[(t+1)&1]);
  }
}

// Round 18
// 130.502 us; speedup vs baseline: 1.9660x; 1.9660x over previous
//
#include <hip/hip_runtime.h>
#include <hip/hip_fp16.h>
#include <math.h>

#define Hh 96
#define Ww 96
#define NPIX 9216
#define RAD 15
#define TAPS 31
#define NCH 144            // chunks of 64 sorted pixels
#define NBIN 4096
#define GRIDB 2048         // buildK/matvec blocks (8192 waves, wave-per-item)
#define EPSV 1e-20f
#define LOG2E 1.4426950408889634f
#define CUT2 42.0f         // box-box prune: k < 2^-30 beyond => safe (err ~1e-5)

// ---- ws layout (4-byte units) ----
#define OFF_F    0                 // 8*NPIX feat_sorted: h0..h4, a, q, pad
#define OFF_Q0   73728             // NPIX  q ping (original order, combine halo)
#define OFF_Q1   82944             // NPIX  q pong
#define OFF_QS   92160             // NPIX  q SORTED order (matvec input)
#define OFF_CBI  101376            // NPIX  bilateral colsum, SORTED order
#define OFF_BV   110592            // NPIX  bilateral q-filter, SORTED order
#define OFF_ROWW 119808            // 96
#define OFF_WTAB 119904            // 32
#define OFF_BBOX 119936            // NCH*12
// int regions
#define OFF_HIST 121664            // 4096
#define OFF_BASE 125760            // 4096
#define OFF_INV  129856            // NPIX  orig n -> sorted pos
#define OFF_OFS  139072            // NCH+1
#define OFF_WORK 139217            // NCH*NCH flat worklist (jg<<8|c)
#define OFF_K    165888            // item stride 2048 u32: fp16 K [item][ipair][j]

__device__ __forceinline__ int color_key(float r, float g, float b){
  int rq = min(15, (int)r >> 4);
  int gq = min(15, (int)g >> 4);
  int bq = min(15, (int)b >> 4);
  int key = 0;
  #pragma unroll
  for (int k=0;k<4;k++){
    key |= ((rq>>k)&1) << (3*k+2);
    key |= ((gq>>k)&1) << (3*k+1);
    key |= ((bq>>k)&1) << (3*k);
  }
  return key;
}

// A: zero BV/CBI/hist + spatial tables
__global__ __launch_bounds__(256) void prepA_kernel(float* __restrict__ ws){
  int idx = blockIdx.x*256 + threadIdx.x;
  int* W = (int*)ws;
  if (idx < NPIX){ ws[OFF_BV+idx]=0.f; ws[OFF_CBI+idx]=0.f; }
  if (idx < NBIN) W[OFF_HIST+idx] = 0;
  if (blockIdx.x == 94 && threadIdx.x < Hh){
    int t = threadIdx.x;
    float s = 0.f;
    for (int yy=0; yy<Hh; ++yy){ float d=(float)(yy-t); s += expf(-d*d*(1.0f/18.0f)); }
    ws[OFF_ROWW + t] = s;                 // full 1-D colsum (spatial norm)
  }
  if (blockIdx.x == 95 && threadIdx.x < TAPS){
    int d = threadIdx.x - RAD;
    ws[OFF_WTAB + threadIdx.x] = expf(-(float)(d*d)*(1.0f/18.0f));
  }
}

// B: color histogram
__global__ __launch_bounds__(256) void prepB_kernel(const float* __restrict__ image,
                                                    float* __restrict__ ws){
  int n = blockIdx.x*256 + threadIdx.x;
  int key = color_key(image[n], image[NPIX+n], image[2*NPIX+n]);
  atomicAdd((int*)ws + OFF_HIST + key, 1);
}

// C: exclusive scan of 4096 bins (1 block)
__global__ __launch_bounds__(256) void prepC_kernel(float* __restrict__ ws){
  __shared__ int part[256];
  const int* hist = (const int*)ws + OFF_HIST;
  int* base = (int*)ws + OFF_BASE;
  int t = threadIdx.x;
  int loc[16]; int s = 0;
  #pragma unroll
  for (int i=0;i<16;i++){ loc[i]=s; s += hist[t*16+i]; }
  part[t] = s; __syncthreads();
  for (int off=1; off<256; off<<=1){
    int v = (t>=off) ? part[t-off] : 0;
    __syncthreads(); part[t] += v; __syncthreads();
  }
  int b = (t==0)?0:part[t-1];
  #pragma unroll
  for (int i=0;i<16;i++) base[t*16+i] = b + loc[i];
}

// D: scatter + sorted feature build (q in F slot 6) + initial q (orig + sorted)
__global__ __launch_bounds__(256) void prepD_kernel(const float* __restrict__ image,
                                                    const float* __restrict__ logits,
                                                    float* __restrict__ ws){
  int n = blockIdx.x*256 + threadIdx.x;
  int* W = (int*)ws;
  float r=image[n], g=image[NPIX+n], bl=image[2*NPIX+n];
  int key = color_key(r,g,bl);
  int pos = atomicAdd(W + OFF_BASE + key, 1);
  W[OFF_INV + n] = pos;
  int y=n/Ww, x=n%Ww;
  const float c=0.7213475205f;    // 0.5/ln2
  const float sc=1.2011224088f;   // sqrt(2c)
  float f0=(float)y*(1.f/160.f), f1=(float)x*(1.f/160.f);
  float f2=r*(1.f/3.f), f3=g*(1.f/3.f), f4=bl*(1.f/3.f);
  float a=c*(f0*f0+f1*f1+f2*f2+f3*f3+f4*f4);
  float q = 1.f/(1.f + __builtin_amdgcn_exp2f((logits[NPIX+n]-logits[n])*LOG2E));
  float* F = ws + OFF_F + (size_t)pos*8;
  F[0]=sc*f0; F[1]=sc*f1; F[2]=sc*f2; F[3]=sc*f3; F[4]=sc*f4;
  F[5]=a; F[6]=q; F[7]=0.f;
  ws[OFF_Q0 + n] = q;
  ws[OFF_QS + pos] = q;
}

// E1: per-chunk 5-D bbox, one wave per chunk
__global__ __launch_bounds__(256) void prepE1_kernel(float* __restrict__ ws){
  const int lane = threadIdx.x & 63, wid = threadIdx.x >> 6;
  int ch = blockIdx.x*4 + wid;
  if (ch >= NCH) return;
  const float* Fp = ws + OFF_F + ((size_t)ch*64 + lane)*8;
  float4 A = *(const float4*)Fp;
  float4 B4 = *(const float4*)(Fp+4);
  float mn[5]={A.x,A.y,A.z,A.w,B4.x}, mx[5]={A.x,A.y,A.z,A.w,B4.x};
  #pragma unroll
  for (int m=32; m; m>>=1){
    #pragma unroll
    for (int d=0;d<5;d++){
      mn[d]=fminf(mn[d], __shfl_xor(mn[d], m));
      mx[d]=fmaxf(mx[d], __shfl_xor(mx[d], m));
    }
  }
  if (lane == 0){
    float* bb = ws + OFF_BBOX + ch*12;
    #pragma unroll
    for (int d=0;d<5;d++){ bb[d]=mn[d]; bb[5+d]=mx[d]; }
  }
}

// E2: cull (box-box) + scan + pack flat worklist (1 block, all LDS)
__global__ __launch_bounds__(256) void prepE2_kernel(float* __restrict__ ws){
  __shared__ float bbl[NCH*12];
  __shared__ int part[256];
  __shared__ int cnt[NCH];
  const int t = threadIdx.x, lane = t & 63, wid = t >> 6;
  int* W = (int*)ws;

  for (int i=t; i<NCH*12; i+=256) bbl[i] = ws[OFF_BBOX + i];
  __syncthreads();

  // pass 1: survivor counts
  for (int jg = wid; jg < NCH; jg += 4){
    const float* jb = &bbl[jg*12];
    int base = 0;
    #pragma unroll
    for (int r2=0;r2<3;r2++){
      int c2 = lane + 64*r2;
      bool sv = false;
      if (c2 < NCH){
        const float* cb = &bbl[c2*12];
        float s2 = 0.f;
        #pragma unroll
        for (int d=0;d<5;d++){
          float gap = fmaxf(0.f, fmaxf(cb[d]-jb[5+d], jb[d]-cb[5+d]));
          s2 = fmaf(gap, gap, s2);
        }
        sv = (s2 <= CUT2);
      }
      base += __popcll(__ballot(sv));
    }
    if (lane == 0) cnt[jg] = base;
  }
  __syncthreads();

  // scan: worklist offsets
  int v = (t < NCH) ? cnt[t] : 0;
  part[t] = v; __syncthreads();
  for (int off=1; off<256; off<<=1){
    int u = (t>=off) ? part[t-off] : 0;
    __syncthreads(); part[t] += u; __syncthreads();
  }
  if (t == 0) W[OFF_OFS] = 0;
  if (t < NCH) W[OFF_OFS + t + 1] = part[t];
  __syncthreads();

  // pass 2: pack worklist entries (jg<<8)|c
  for (int jg = wid; jg < NCH; jg += 4){
    const float* jb = &bbl[jg*12];
    int base = (jg == 0) ? 0 : part[jg-1];
    #pragma unroll
    for (int r2=0;r2<3;r2++){
      int c2 = lane + 64*r2;
      bool sv = false;
      if (c2 < NCH){
        const float* cb = &bbl[c2*12];
        float s2 = 0.f;
        #pragma unroll
        for (int d=0;d<5;d++){
          float gap = fmaxf(0.f, fmaxf(cb[d]-jb[5+d], jb[d]-cb[5+d]));
          s2 = fmaf(gap, gap, s2);
        }
        sv = (s2 <= CUT2);
      }
      unsigned long long m = __ballot(sv);
      if (sv){
        int pos = __popcll(m & ((1ull<<lane)-1ull));
        W[OFF_WORK + base + pos] = (jg<<8) | c2;
      }
      base += __popcll(m);
    }
  }
}

// buildK: wave-per-item grid-stride (R11 schedule). Chunk staged in wave-
// private LDS (q rides in slot 6); 2 exp chains; K stored [item][ipair][j]
// => coalesced 256B store per ii. Per-item coalesced atomics (sorted order).
__global__ __launch_bounds__(256) void buildK_kernel(float* __restrict__ ws){
  __shared__ float chunk[4][512];
  const int lane = threadIdx.x & 63, wid = threadIdx.x >> 6;
  int* W = (int*)ws;
  const int T = W[OFF_OFS + NCH];
  const int* work = W + OFF_WORK;
  const float* F  = ws + OFF_F;
  unsigned int* Kb = (unsigned int*)ws + OFF_K;
  float* s = &chunk[wid][0];

  for (int it = blockIdx.x*4 + wid; it < T; it += GRIDB*4){
    int en = work[it];
    int jg = en >> 8, c = en & 255;
    int js = jg*64 + lane;
    float4 jA = *(const float4*)(F + (size_t)js*8);
    float4 jB = *(const float4*)(F + (size_t)js*8 + 4);
    const float h0=jA.x,h1=jA.y,h2=jA.z,h3=jA.w,h4=jB.x,na=-jB.y;

    const float* src = F + (size_t)c*512;
    *(float4*)(s + lane*8)     = *(const float4*)(src + lane*8);
    *(float4*)(s + lane*8 + 4) = *(const float4*)(src + lane*8 + 4);

    float aB0=0.f,aB1=0.f,aC0=0.f,aC1=0.f;
    unsigned int* Kit = Kb + (size_t)it*2048 + lane;
    #pragma unroll 4
    for (int ii=0; ii<32; ii++){
      float4 w0 = *(const float4*)(s + 2*ii*8);
      float4 w1 = *(const float4*)(s + 2*ii*8 + 4);
      float e0 = na - w1.y;
      e0=fmaf(h0,w0.x,e0); e0=fmaf(h1,w0.y,e0); e0=fmaf(h2,w0.z,e0);
      e0=fmaf(h3,w0.w,e0); e0=fmaf(h4,w1.x,e0);
      float k0 = __builtin_amdgcn_exp2f(e0);
      float4 u0 = *(const float4*)(s + (2*ii+1)*8);
      float4 u1 = *(const float4*)(s + (2*ii+1)*8 + 4);
      float e1 = na - u1.y;
      e1=fmaf(h0,u0.x,e1); e1=fmaf(h1,u0.y,e1); e1=fmaf(h2,u0.z,e1);
      e1=fmaf(h3,u0.w,e1); e1=fmaf(h4,u1.x,e1);
      float k1 = __builtin_amdgcn_exp2f(e1);
      aC0 += k0; aC1 += k1;
      aB0 = fmaf(k0, w1.z, aB0);            // q_i staged in slot 6
      aB1 = fmaf(k1, u1.z, aB1);
      __half2 hv = __floats2half2_rn(k0, k1);
      Kit[ii*64] = *reinterpret_cast<unsigned int*>(&hv);   // coalesced 256B
    }
    atomicAdd(ws + OFF_BV  + js, aB0 + aB1);
    atomicAdd(ws + OFF_CBI + js, aC0 + aC1);
  }
}

// matvec: wave-per-item grid-stride; coalesced u32 K loads; q broadcast from
// wave-private LDS; per-item coalesced atomic.
__global__ __launch_bounds__(256) void matvec_kernel(float* __restrict__ ws){
  __shared__ float qsh[4][64];
  const int lane = threadIdx.x & 63, wid = threadIdx.x >> 6;
  const int* W = (const int*)ws;
  const int T = W[OFF_OFS + NCH];
  const int* work = W + OFF_WORK;
  const unsigned int* Kb = (const unsigned int*)ws + OFF_K;
  float* ql = &qsh[wid][0];

  for (int it = blockIdx.x*4 + wid; it < T; it += GRIDB*4){
    int en = work[it];
    int c = en & 255;
    int js = (en >> 8)*64 + lane;
    ql[lane] = ws[OFF_QS + c*64 + lane];
    const unsigned int* Kit = Kb + (size_t)it*2048 + lane;
    float a0=0.f, a1=0.f;
    #pragma unroll 8
    for (int ii=0; ii<32; ii++){
      unsigned int kk = Kit[ii*64];
      __half2 hv = *reinterpret_cast<__half2*>(&kk);
      a0 = fmaf(__low2float(hv),  ql[2*ii],   a0);
      a1 = fmaf(__high2float(hv), ql[2*ii+1], a1);
    }
    atomicAdd(ws + OFF_BV + js, a0 + a1);
  }
}

// combine: separable spatial conv + message/compat/update + next-iter q.
__global__ __launch_bounds__(256) void combine_kernel(const float* __restrict__ logits,
                                                      const float* __restrict__ Wsp,
                                                      const float* __restrict__ Wbi,
                                                      const float* __restrict__ Cm,
                                                      float* __restrict__ ws,
                                                      float* __restrict__ out,
                                                      const float* __restrict__ qsrc,
                                                      float* __restrict__ qdst){
  __shared__ float tq[46][48];
  __shared__ float tr[46][17];
  __shared__ float wt[TAPS];
  int tx = threadIdx.x & 15, ty = threadIdx.x >> 4;
  int bx = blockIdx.x % 6, by = blockIdx.x / 6;
  int x0 = bx*16, y0 = by*16;

  for (int idx = threadIdx.x; idx < 46*46; idx += 256){
    int ly = idx / 46, lx = idx % 46;
    int gy = y0 - RAD + ly, gx = x0 - RAD + lx;
    float v = 0.f;
    if (gy >= 0 && gy < Hh && gx >= 0 && gx < Ww) v = qsrc[gy*Ww + gx];
    tq[ly][lx] = v;
  }
  if (threadIdx.x < TAPS) wt[threadIdx.x] = ws[OFF_WTAB + threadIdx.x];
  __syncthreads();

  for (int idx = threadIdx.x; idx < 46*16; idx += 256){
    int ly = idx >> 4, lx = idx & 15;
    float in = 0.f;
    #pragma unroll
    for (int dx=0; dx<TAPS; dx++) in = fmaf(wt[dx], tq[ly][lx+dx], in);
    tr[ly][lx] = in;
  }
  __syncthreads();

  int y = y0 + ty, x = x0 + tx, j = y*Ww + x;
  float S = 0.f;
  #pragma unroll
  for (int dy=0; dy<TAPS; dy++) S = fmaf(wt[dy], tr[ty+dy][tx], S);

  int js = ((const int*)ws)[OFF_INV + j];
  float Bv = ws[OFF_BV + js];
  ws[OFF_BV + js] = 0.f;                      // reset for next iteration's atomics
  float Cb = ws[OFF_CBI + js];
  float nb  = 1.0f/(Cb + EPSV);
  float Csp = ws[OFF_ROWW + y] * ws[OFF_ROWW + x];
  float nsp = 1.0f/(Csp + EPSV);

  float sp0 = S*nsp,  sp1 = (Csp - S)*nsp;    // q1 = 1 - q0 identity
  float bi0 = Bv*nb,  bi1 = (Cb - Bv)*nb;

  float m0 = Wsp[0]*sp0 + Wsp[1]*sp1 + Wbi[0]*bi0 + Wbi[1]*bi1;
  float m1 = Wsp[2]*sp0 + Wsp[3]*sp1 + Wbi[2]*bi0 + Wbi[3]*bi1;
  float cm0 = Cm[0]*m0 + Cm[1]*m1;
  float cm1 = Cm[2]*m0 + Cm[3]*m1;

  float o0 = logits[j]        - cm0;
  float o1 = logits[NPIX + j] - cm1;
  out[j]        = o0;
  out[NPIX + j] = o1;

  float qn = 1.0f / (1.0f + __builtin_amdgcn_exp2f((o1-o0)*LOG2E));
  qdst[j] = qn;
  ws[OFF_QS + js] = qn;
}

extern "C" void kernel_launch(void* const* d_in, const int* in_sizes, int n_in,
                              void* d_out, int out_size, void* d_ws, size_t ws_size,
                              hipStream_t stream){
  const float* image  = (const float*)d_in[0];
  const float* logits = (const float*)d_in[1];
  const float* Wsp    = (const float*)d_in[2];
  const float* Wbi    = (const float*)d_in[3];
  const float* Cm     = (const float*)d_in[4];
  float* out = (float*)d_out;
  float* ws  = (float*)d_ws;

  float* qbuf[2] = { ws + OFF_Q0, ws + OFF_Q1 };

  prepA_kernel <<<96, 256, 0, stream>>>(ws);
  prepB_kernel <<<36, 256, 0, stream>>>(image, ws);
  prepC_kernel <<<1, 256, 0, stream>>>(ws);
  prepD_kernel <<<36, 256, 0, stream>>>(image, logits, ws);
  prepE1_kernel<<<36, 256, 0, stream>>>(ws);
  prepE2_kernel<<<1, 256, 0, stream>>>(ws);

  // iteration 0: build fp16 K + colsum + q-filter in one pass
  buildK_kernel<<<GRIDB, 256, 0, stream>>>(ws);
  combine_kernel<<<36, 256, 0, stream>>>(logits, Wsp, Wbi, Cm, ws, out,
                                         qbuf[0], qbuf[1]);
  // iterations 1..4: stream K
  for (int t=1; t<5; ++t){
    matvec_kernel<<<GRIDB, 256, 0, stream>>>(ws);
    combine_kernel<<<36, 256, 0, stream>>>(logits, Wsp, Wbi, Cm, ws, out,
                                           qbuf[t&1], qbuf[(t+1)&1]);
  }
}